// Round 9
// baseline (444.885 us; speedup 1.0000x reference)
//
#include <hip/hip_runtime.h>
#include <math.h>

#define NROW   8000
#define NFEATD 512
#define NHID   128
#define NCLS   64
#define CAP    64
#define EPSV   1e-12f
#define ALV    0.1f
#define NTRAIN 500
#define NQ4    16000000   // 8000*8000/4 f32x4 elements of adj

typedef __attribute__((ext_vector_type(8))) short bf16x8;
typedef __attribute__((ext_vector_type(4))) float f32x4;

__device__ __forceinline__ float wsum(float v) {
#pragma unroll
  for (int off = 32; off > 0; off >>= 1) v += __shfl_xor(v, off, 64);
  return v;
}
__device__ __forceinline__ float wmax(float v) {
#pragma unroll
  for (int off = 32; off > 0; off >>= 1) v = fmaxf(v, __shfl_xor(v, off, 64));
  return v;
}
__device__ __forceinline__ unsigned short f2bf(float f) {   // RTN-even
  unsigned int u = __float_as_uint(f);
  unsigned int r = u + 0x7FFFu + ((u >> 16) & 1u);
  return (unsigned short)(r >> 16);
}

// ---------------------------------------------------------------------------
// Prep: cast W0 -> bf16 fragment-ordered w0s (128 KB, L2-hot) AND zero the
// per-row edge counters. Grid 64 x 256.
// ---------------------------------------------------------------------------
__global__ __launch_bounds__(256) void k_prep(const float* __restrict__ W0,
                                              unsigned short* __restrict__ w0s,
                                              int* __restrict__ gcnt) {
  int e = blockIdx.x * 1024 + threadIdx.x;
  for (int i = 0; i < 4; ++i, e += 256) {
    int c = e >> 12, n = (e >> 5) & 127, k = e & 31;
    w0s[e] = f2bf(W0[(size_t)(c * 32 + k) * NHID + n]);
  }
  int z = blockIdx.x * 256 + threadIdx.x;
  if (z < NROW) gcnt[z] = 0;
}

// ---------------------------------------------------------------------------
// Adj scan, copy-shaped: grid-stride over the flat 256MB array. 2048 blocks
// x 256 thr, 4 batches x 8 f32x4 loads in flight per thread, <=64 VGPR
// (launch_bounds min-waves=8 -> 8 waves/SIMD, m13-copy occupancy). Row/col
// decoded only in the rare (~0.2%) nonzero branch; slots claimed via global
// atomicAdd (order within a row is irrelevant downstream).
// ---------------------------------------------------------------------------
__global__ __launch_bounds__(256, 8) void k_csr(const float* __restrict__ adj,
                                                int* __restrict__ cols,
                                                int* __restrict__ gcnt) {
  const int t = blockIdx.x * 256 + threadIdx.x;   // 0..524287
  const f32x4* a4 = (const f32x4*)adj;
  const f32x4 z4 = {0.f, 0.f, 0.f, 0.f};
#pragma unroll
  for (int b = 0; b < 4; ++b) {
    f32x4 v[8];
#pragma unroll
    for (int i = 0; i < 8; ++i) {
      int idx = t + ((b * 8 + i) << 19);          // stride 524288
      v[i] = (idx < NQ4) ? a4[idx] : z4;
    }
#pragma unroll
    for (int i = 0; i < 8; ++i) {
      f32x4 w = v[i];
      if (w[0] != 0.f || w[1] != 0.f || w[2] != 0.f || w[3] != 0.f) {
        int idx = t + ((b * 8 + i) << 19);
        int row = idx / 2000;                     // 2000 f32x4 per row
        int colb = (idx - row * 2000) << 2;
        int* rowcols = cols + row * CAP;
#pragma unroll
        for (int j = 0; j < 4; ++j) {
          if (w[j] != 0.f) {
            int p = atomicAdd(gcnt + row, 1);
            if (p < CAP) rowcols[p] = colb + j;
          }
        }
      }
    }
  }
}

// ---------------------------------------------------------------------------
// GEMM tile (500 x 16 rows): h = relu(x@W0+b0) via bf16 MFMA (A cast
// in-register, B frags 16B loads from L2-hot w0s), then Pseudo = h@W1+b1
// (+injection via bsearch in sorted idx) and y_hat = softmax from LDS.
// ---------------------------------------------------------------------------
__global__ __launch_bounds__(256) void k_gemm(const float* __restrict__ x,
                                              const unsigned short* __restrict__ w0s,
                                              const float* __restrict__ b0,
                                              const float* __restrict__ W1,
                                              const float* __restrict__ b1,
                                              const int* __restrict__ idx,
                                              const float* __restrict__ yl,
                                              float* __restrict__ h,
                                              float* __restrict__ yh,
                                              float* __restrict__ outP) {
  __shared__ float hs[16][NHID];
  __shared__ int ids[NTRAIN];
  const int t = threadIdx.x;
  const int lane = t & 63;
  const int w = t >> 6;
  const int m = lane & 15, q = lane >> 4;
  const int row0 = blockIdx.x * 16;
  const int wcol = w * 32;
  for (int i = t; i < NTRAIN; i += 256) ids[i] = idx[i];
  const float* ap = x + (size_t)(row0 + m) * NFEATD + q * 8;
  f32x4 acc0 = {0.f, 0.f, 0.f, 0.f}, acc1 = {0.f, 0.f, 0.f, 0.f};

  for (int c = 0; c < 16; ++c) {
    float4 a0 = *(const float4*)(ap + c * 32);
    float4 a1 = *(const float4*)(ap + c * 32 + 4);
    bf16x8 bv0 = *(const bf16x8*)(w0s + c * 4096 + (wcol + m) * 32 + q * 8);
    bf16x8 bv1 = *(const bf16x8*)(w0s + c * 4096 + (wcol + 16 + m) * 32 + q * 8);
    bf16x8 av;
    av[0] = (short)f2bf(a0.x); av[1] = (short)f2bf(a0.y);
    av[2] = (short)f2bf(a0.z); av[3] = (short)f2bf(a0.w);
    av[4] = (short)f2bf(a1.x); av[5] = (short)f2bf(a1.y);
    av[6] = (short)f2bf(a1.z); av[7] = (short)f2bf(a1.w);
    acc0 = __builtin_amdgcn_mfma_f32_16x16x32_bf16(av, bv0, acc0, 0, 0, 0);
    acc1 = __builtin_amdgcn_mfma_f32_16x16x32_bf16(av, bv1, acc1, 0, 0, 0);
  }
  const float bc0 = b0[wcol + m], bc1 = b0[wcol + 16 + m];
#pragma unroll
  for (int reg = 0; reg < 4; ++reg) {
    int lr = q * 4 + reg;
    float h0v = fmaxf(acc0[reg] + bc0, 0.f);
    float h1v = fmaxf(acc1[reg] + bc1, 0.f);
    h[(size_t)(row0 + lr) * NHID + wcol + m] = h0v;
    h[(size_t)(row0 + lr) * NHID + wcol + 16 + m] = h1v;
    hs[lr][wcol + m] = h0v;
    hs[lr][wcol + 16 + m] = h1v;
  }
  __syncthreads();
  const float b1v = b1[lane];
#pragma unroll
  for (int rr = 0; rr < 4; ++rr) {
    const int lr = w * 4 + rr;
    const int grow = row0 + lr;
    float acc = b1v;
#pragma unroll 8
    for (int k = 0; k < NHID; ++k) acc += hs[lr][k] * W1[k * NCLS + lane];
    int lo = 0, hi = NTRAIN;
    while (lo < hi) { int mid = (lo + hi) >> 1; if (ids[mid] < grow) lo = mid + 1; else hi = mid; }
    int lb = lo; hi = NTRAIN;
    while (lo < hi) { int mid = (lo + hi) >> 1; if (ids[mid] <= grow) lo = mid + 1; else hi = mid; }
    int count = lo - lb;
    if (count) acc += ALV * (float)count * yl[(size_t)grow * NCLS + lane];
    outP[(size_t)grow * NCLS + lane] = acc;
    float mx = wmax(acc);
    float e = __expf(acc - mx);
    float s = wsum(e);
    yh[(size_t)grow * NCLS + lane] = e / s;
  }
}

// ---------------------------------------------------------------------------
// Fused edge weights + propagation layer 1. Grid 2000 x 256, wave per row.
// ---------------------------------------------------------------------------
__global__ __launch_bounds__(256) void k_ewp1(const float* __restrict__ yh,
                                              const float* __restrict__ h,
                                              const int* __restrict__ cols,
                                              const int* __restrict__ gcnt,
                                              float* __restrict__ wv,
                                              float* __restrict__ lib) {
  __shared__ float yrow[4][NCLS];
  const int w = threadIdx.x >> 6, lane = threadIdx.x & 63;
  const int row = blockIdx.x * 4 + w;
  const int ne = min(gcnt[row], CAP);
  int jv = 0;
  if (lane < ne) jv = cols[row * CAP + lane];
  yrow[w][lane] = yh[(size_t)row * NCLS + lane];
  __syncthreads();
  float dot = 0.f;
  if (lane < ne) {
    const float4* jp = (const float4*)(yh + (size_t)jv * NCLS);
    const float4* rp = (const float4*)yrow[w];
#pragma unroll
    for (int c4 = 0; c4 < NCLS / 4; ++c4) {
      float4 a = rp[c4], b = jp[c4];
      dot += a.x * b.x + a.y * b.y + a.z * b.z + a.w * b.w;
    }
  }
  float rs = wsum(dot);
  float myw = dot * (1.f / fmaxf(rs, EPSV));
  if (lane < ne) wv[row * CAP + lane] = myw;
  float a0 = 0.f, a1 = 0.f;
  for (int e = 0; e < ne; ++e) {
    int j = __shfl(jv, e, 64);
    float wt = __shfl(myw, e, 64);
    a0 += wt * h[(size_t)j * NHID + lane];
    a1 += wt * h[(size_t)j * NHID + 64 + lane];
  }
  float v0 = (1.f - ALV) * a0 + ALV * h[(size_t)row * NHID + lane];
  float v1 = (1.f - ALV) * a1 + ALV * h[(size_t)row * NHID + 64 + lane];
  float s = wsum(v0 * v0 + v1 * v1);
  float inv = 1.f / fmaxf(sqrtf(s), EPSV);
  lib[(size_t)row * NHID + lane] = v0 * inv;
  lib[(size_t)row * NHID + 64 + lane] = v1 * inv;
}

// ---------------------------------------------------------------------------
// Fused propagation layer 2 + final head. Grid 2000 x 256, wave per row.
// ---------------------------------------------------------------------------
__global__ __launch_bounds__(256) void k_p2fin(const float* __restrict__ lib,
                                               const float* __restrict__ h,
                                               const int* __restrict__ cols,
                                               const int* __restrict__ gcnt,
                                               const float* __restrict__ wv,
                                               const float* __restrict__ W2,
                                               const float* __restrict__ b2,
                                               float* __restrict__ out) {
  __shared__ float lrow[4][NHID];
  const int w = threadIdx.x >> 6, lane = threadIdx.x & 63;
  const int row = blockIdx.x * 4 + w;
  const int ne = min(gcnt[row], CAP);
  int jv = 0; float wt = 0.f;
  if (lane < ne) { jv = cols[row * CAP + lane]; wt = wv[row * CAP + lane]; }
  float a0 = 0.f, a1 = 0.f;
  for (int e = 0; e < ne; ++e) {
    int j = __shfl(jv, e, 64);
    float we = __shfl(wt, e, 64);
    a0 += we * lib[(size_t)j * NHID + lane];
    a1 += we * lib[(size_t)j * NHID + 64 + lane];
  }
  float v0 = (1.f - ALV) * a0 + ALV * h[(size_t)row * NHID + lane];
  float v1 = (1.f - ALV) * a1 + ALV * h[(size_t)row * NHID + 64 + lane];
  float s = wsum(v0 * v0 + v1 * v1);
  float inv = 1.f / fmaxf(sqrtf(s), EPSV);
  lrow[w][lane] = v0 * inv;
  lrow[w][lane + 64] = v1 * inv;
  __syncthreads();
  float acc = b2[lane];
#pragma unroll 8
  for (int k = 0; k < NHID; ++k) acc += lrow[w][k] * W2[k * NCLS + lane];
  float mx = wmax(acc);
  float l = acc - mx;
  float se = wsum(__expf(l));
  out[(size_t)row * NCLS + lane] = l - __logf(se);
}

// ---------------------------------------------------------------------------
extern "C" void kernel_launch(void* const* d_in, const int* in_sizes, int n_in,
                              void* d_out, int out_size, void* d_ws, size_t ws_size,
                              hipStream_t stream) {
  const float* x   = (const float*)d_in[0];
  const float* adj = (const float*)d_in[1];
  const float* yl  = (const float*)d_in[2];
  const int*   idx = (const int*)d_in[3];
  const float* W0  = (const float*)d_in[4];
  const float* b0  = (const float*)d_in[5];
  const float* W1  = (const float*)d_in[6];
  const float* b1  = (const float*)d_in[7];
  const float* W2  = (const float*)d_in[8];
  const float* b2  = (const float*)d_in[9];
  float* out = (float*)d_out;

  char* wsb = (char*)d_ws;
  float* h    = (float*)(wsb);                  // 4,096,000 B
  float* lib  = (float*)(wsb + 4096000);        // 4,096,000 B
  float* yh   = (float*)(wsb + 8192000);        // 2,048,000 B
  float* wv   = (float*)(wsb + 10240000);       // 2,048,000 B
  int*   cols = (int*)(wsb + 12288000);         // 2,048,000 B
  int*   gcnt = (int*)(wsb + 14336000);         //    32,000 B
  unsigned short* w0s = (unsigned short*)(wsb + 14368000);  // 131,072 B

  k_prep  <<<64,   256, 0, stream>>>(W0, w0s, gcnt);
  k_csr   <<<2048, 256, 0, stream>>>(adj, cols, gcnt);
  k_gemm  <<<500,  256, 0, stream>>>(x, w0s, b0, W1, b1, idx, yl,
                                     h, yh, out + 512000);
  k_ewp1  <<<2000, 256, 0, stream>>>(yh, h, cols, gcnt, wv, lib);
  k_p2fin <<<2000, 256, 0, stream>>>(lib, h, cols, gcnt, wv, W2, b2, out);
}

// Round 10
// 435.309 us; speedup vs baseline: 1.0220x; 1.0220x over previous
//
#include <hip/hip_runtime.h>
#include <math.h>

#define NROW   8000
#define NFEATD 512
#define NHID   128
#define NCLS   64
#define CAP    64
#define EPSV   1e-12f
#define ALV    0.1f
#define NTRAIN 500

typedef __attribute__((ext_vector_type(8))) short bf16x8;
typedef __attribute__((ext_vector_type(4))) float f32x4;

__device__ __forceinline__ float wsum(float v) {
#pragma unroll
  for (int off = 32; off > 0; off >>= 1) v += __shfl_xor(v, off, 64);
  return v;
}
__device__ __forceinline__ float wmax(float v) {
#pragma unroll
  for (int off = 32; off > 0; off >>= 1) v = fmaxf(v, __shfl_xor(v, off, 64));
  return v;
}
__device__ __forceinline__ unsigned short f2bf(float f) {   // RTN-even
  unsigned int u = __float_as_uint(f);
  unsigned int r = u + 0x7FFFu + ((u >> 16) & 1u);
  return (unsigned short)(r >> 16);
}
__device__ __forceinline__ unsigned pack4(float4 v) {
  return (unsigned)(v.x != 0.f) | ((unsigned)(v.y != 0.f) << 1) |
         ((unsigned)(v.z != 0.f) << 2) | ((unsigned)(v.w != 0.f) << 3);
}

// ---------------------------------------------------------------------------
// Prep: cast W0 -> bf16 fragment-ordered w0s (128 KB, L2-hot). Grid 64 x 256.
// ---------------------------------------------------------------------------
__global__ __launch_bounds__(256) void k_prep(const float* __restrict__ W0,
                                              unsigned short* __restrict__ w0s) {
  int e = blockIdx.x * 1024 + threadIdx.x;
  for (int i = 0; i < 4; ++i, e += 256) {
    int c = e >> 12, n = (e >> 5) & 127, k = e & 31;
    w0s[e] = f2bf(W0[(size_t)(c * 32 + k) * NHID + n]);
  }
}

// ---------------------------------------------------------------------------
// Fused front-end. Grid 2500 x 256.
//   blockIdx % 5 == 4 : GEMM tile (500 x 16 rows): h = relu(x@W0+b0) via
//                       bf16 MFMA; then Pseudo/injection/softmax from LDS.
//   else              : scan role, 4 adj rows: 8 coalesced float4 loads ->
//                       one 32-bit presence mask -> one 4B store per thread.
//                       NO branches, NO atomics, NO division in the stream.
//                       bit 4i+j of mask32[row*256+t] = adj[row][(i*256+t)*4+j]!=0
// ---------------------------------------------------------------------------
__global__ __launch_bounds__(256) void k_front(const float* __restrict__ adj,
                                               const float* __restrict__ x,
                                               const unsigned short* __restrict__ w0s,
                                               const float* __restrict__ b0,
                                               const float* __restrict__ W1,
                                               const float* __restrict__ b1,
                                               const int* __restrict__ idx,
                                               const float* __restrict__ yl,
                                               float* __restrict__ h,
                                               float* __restrict__ yh,
                                               float* __restrict__ outP,
                                               unsigned* __restrict__ mask32) {
  __shared__ float hs[16][NHID];   // GEMM role only (8 KB)
  __shared__ int ids[NTRAIN];      // GEMM role only (2 KB)
  const int t = threadIdx.x;
  const int lane = t & 63;
  const int g = blockIdx.x / 5;
  const int r = blockIdx.x - g * 5;

  if (r == 4) {
    // ---------------- GEMM + pseudo/softmax role ----------------
    const int w = t >> 6;
    const int m = lane & 15, q = lane >> 4;
    const int row0 = g * 16;
    const int wcol = w * 32;
    for (int i = t; i < NTRAIN; i += 256) ids[i] = idx[i];
    const float* ap = x + (size_t)(row0 + m) * NFEATD + q * 8;
    f32x4 acc0 = {0.f, 0.f, 0.f, 0.f}, acc1 = {0.f, 0.f, 0.f, 0.f};

    for (int c = 0; c < 16; ++c) {
      float4 a0 = *(const float4*)(ap + c * 32);
      float4 a1 = *(const float4*)(ap + c * 32 + 4);
      bf16x8 bv0 = *(const bf16x8*)(w0s + c * 4096 + (wcol + m) * 32 + q * 8);
      bf16x8 bv1 = *(const bf16x8*)(w0s + c * 4096 + (wcol + 16 + m) * 32 + q * 8);
      bf16x8 av;
      av[0] = (short)f2bf(a0.x); av[1] = (short)f2bf(a0.y);
      av[2] = (short)f2bf(a0.z); av[3] = (short)f2bf(a0.w);
      av[4] = (short)f2bf(a1.x); av[5] = (short)f2bf(a1.y);
      av[6] = (short)f2bf(a1.z); av[7] = (short)f2bf(a1.w);
      acc0 = __builtin_amdgcn_mfma_f32_16x16x32_bf16(av, bv0, acc0, 0, 0, 0);
      acc1 = __builtin_amdgcn_mfma_f32_16x16x32_bf16(av, bv1, acc1, 0, 0, 0);
    }
    const float bc0 = b0[wcol + m], bc1 = b0[wcol + 16 + m];
#pragma unroll
    for (int reg = 0; reg < 4; ++reg) {
      int lr = q * 4 + reg;
      float h0v = fmaxf(acc0[reg] + bc0, 0.f);
      float h1v = fmaxf(acc1[reg] + bc1, 0.f);
      h[(size_t)(row0 + lr) * NHID + wcol + m] = h0v;
      h[(size_t)(row0 + lr) * NHID + wcol + 16 + m] = h1v;
      hs[lr][wcol + m] = h0v;
      hs[lr][wcol + 16 + m] = h1v;
    }
    __syncthreads();
    const float b1v = b1[lane];
#pragma unroll
    for (int rr = 0; rr < 4; ++rr) {
      const int lr = w * 4 + rr;
      const int grow = row0 + lr;
      float acc = b1v;
#pragma unroll 8
      for (int k = 0; k < NHID; ++k) acc += hs[lr][k] * W1[k * NCLS + lane];
      int lo = 0, hi = NTRAIN;
      while (lo < hi) { int mid = (lo + hi) >> 1; if (ids[mid] < grow) lo = mid + 1; else hi = mid; }
      int lb = lo; hi = NTRAIN;
      while (lo < hi) { int mid = (lo + hi) >> 1; if (ids[mid] <= grow) lo = mid + 1; else hi = mid; }
      int count = lo - lb;
      if (count) acc += ALV * (float)count * yl[(size_t)grow * NCLS + lane];
      outP[(size_t)grow * NCLS + lane] = acc;
      float mx = wmax(acc);
      float e = __expf(acc - mx);
      float s = wsum(e);
      yh[(size_t)grow * NCLS + lane] = e / s;
    }
  } else {
    // ---------------- Scan role: pure stream -> presence masks ------------
    const int s = g * 4 + r;          // 0..1999, rows s*4 .. s*4+3
    const float4 z4 = {0.f, 0.f, 0.f, 0.f};
    for (int rr = 0; rr < 4; ++rr) {
      const int row = s * 4 + rr;
      const float4* rp = (const float4*)(adj + (size_t)row * NROW);
      float4 v[8];
#pragma unroll
      for (int i = 0; i < 7; ++i) v[i] = rp[t + (i << 8)];
      v[7] = (t < 208) ? rp[t + 1792] : z4;   // 2000 float4 per row
      unsigned mask = pack4(v[0]) | (pack4(v[1]) << 4) | (pack4(v[2]) << 8) |
                      (pack4(v[3]) << 12) | (pack4(v[4]) << 16) |
                      (pack4(v[5]) << 20) | (pack4(v[6]) << 24) |
                      (pack4(v[7]) << 28);
      mask32[row * 256 + t] = mask;
    }
  }
}

// ---------------------------------------------------------------------------
// Mask decode + edge weights + propagation layer 1. Grid 2000 x 256, wave/row.
// Decode: lane reads 4 masks, claims slots via per-wave LDS counter, builds
// the col list in LDS (and mirrors to global for k_p2fin).
// ---------------------------------------------------------------------------
__global__ __launch_bounds__(256) void k_ewp1(const unsigned* __restrict__ mask32,
                                              const float* __restrict__ yh,
                                              const float* __restrict__ h,
                                              int* __restrict__ cols,
                                              int* __restrict__ nnz,
                                              float* __restrict__ wv,
                                              float* __restrict__ lib) {
  __shared__ float yrow[4][NCLS];
  __shared__ int lcnt[4];
  __shared__ int lcols[4][CAP];
  const int w = threadIdx.x >> 6, lane = threadIdx.x & 63;
  const int row = blockIdx.x * 4 + w;
  if (lane == 0) lcnt[w] = 0;
  yrow[w][lane] = yh[(size_t)row * NCLS + lane];
  // decode this row's 256 masks (wave-private LDS, no cross-wave barrier)
#pragma unroll
  for (int c = 0; c < 4; ++c) {
    unsigned mm = mask32[row * 256 + c * 64 + lane];
    const int tcol = c * 64 + lane;
    while (mm) {
      int b = __ffs(mm) - 1;
      mm &= mm - 1;
      int col = ((((b >> 2) << 8) + tcol) << 2) + (b & 3);
      int p = atomicAdd(&lcnt[w], 1);
      if (p < CAP) lcols[w][p] = col;
    }
  }
  __syncthreads();
  const int ne = min(lcnt[w], CAP);
  if (lane == 0) nnz[row] = ne;
  int jv = 0;
  if (lane < ne) { jv = lcols[w][lane]; cols[row * CAP + lane] = jv; }
  float dot = 0.f;
  if (lane < ne) {
    const float4* jp = (const float4*)(yh + (size_t)jv * NCLS);
    const float4* rp = (const float4*)yrow[w];
#pragma unroll
    for (int c4 = 0; c4 < NCLS / 4; ++c4) {
      float4 a = rp[c4], b = jp[c4];
      dot += a.x * b.x + a.y * b.y + a.z * b.z + a.w * b.w;
    }
  }
  float rs = wsum(dot);
  float myw = dot * (1.f / fmaxf(rs, EPSV));
  if (lane < ne) wv[row * CAP + lane] = myw;
  float a0 = 0.f, a1 = 0.f;
  for (int e = 0; e < ne; ++e) {
    int j = __shfl(jv, e, 64);
    float wt = __shfl(myw, e, 64);
    a0 += wt * h[(size_t)j * NHID + lane];
    a1 += wt * h[(size_t)j * NHID + 64 + lane];
  }
  float v0 = (1.f - ALV) * a0 + ALV * h[(size_t)row * NHID + lane];
  float v1 = (1.f - ALV) * a1 + ALV * h[(size_t)row * NHID + 64 + lane];
  float s = wsum(v0 * v0 + v1 * v1);
  float inv = 1.f / fmaxf(sqrtf(s), EPSV);
  lib[(size_t)row * NHID + lane] = v0 * inv;
  lib[(size_t)row * NHID + 64 + lane] = v1 * inv;
}

// ---------------------------------------------------------------------------
// Fused propagation layer 2 + final head. Grid 2000 x 256, wave per row.
// ---------------------------------------------------------------------------
__global__ __launch_bounds__(256) void k_p2fin(const float* __restrict__ lib,
                                               const float* __restrict__ h,
                                               const int* __restrict__ cols,
                                               const int* __restrict__ nnz,
                                               const float* __restrict__ wv,
                                               const float* __restrict__ W2,
                                               const float* __restrict__ b2,
                                               float* __restrict__ out) {
  __shared__ float lrow[4][NHID];
  const int w = threadIdx.x >> 6, lane = threadIdx.x & 63;
  const int row = blockIdx.x * 4 + w;
  const int ne = min(nnz[row], CAP);
  int jv = 0; float wt = 0.f;
  if (lane < ne) { jv = cols[row * CAP + lane]; wt = wv[row * CAP + lane]; }
  float a0 = 0.f, a1 = 0.f;
  for (int e = 0; e < ne; ++e) {
    int j = __shfl(jv, e, 64);
    float we = __shfl(wt, e, 64);
    a0 += we * lib[(size_t)j * NHID + lane];
    a1 += we * lib[(size_t)j * NHID + 64 + lane];
  }
  float v0 = (1.f - ALV) * a0 + ALV * h[(size_t)row * NHID + lane];
  float v1 = (1.f - ALV) * a1 + ALV * h[(size_t)row * NHID + 64 + lane];
  float s = wsum(v0 * v0 + v1 * v1);
  float inv = 1.f / fmaxf(sqrtf(s), EPSV);
  lrow[w][lane] = v0 * inv;
  lrow[w][lane + 64] = v1 * inv;
  __syncthreads();
  float acc = b2[lane];
#pragma unroll 8
  for (int k = 0; k < NHID; ++k) acc += lrow[w][k] * W2[k * NCLS + lane];
  float mx = wmax(acc);
  float l = acc - mx;
  float se = wsum(__expf(l));
  out[(size_t)row * NCLS + lane] = l - __logf(se);
}

// ---------------------------------------------------------------------------
extern "C" void kernel_launch(void* const* d_in, const int* in_sizes, int n_in,
                              void* d_out, int out_size, void* d_ws, size_t ws_size,
                              hipStream_t stream) {
  const float* x   = (const float*)d_in[0];
  const float* adj = (const float*)d_in[1];
  const float* yl  = (const float*)d_in[2];
  const int*   idx = (const int*)d_in[3];
  const float* W0  = (const float*)d_in[4];
  const float* b0  = (const float*)d_in[5];
  const float* W1  = (const float*)d_in[6];
  const float* b1  = (const float*)d_in[7];
  const float* W2  = (const float*)d_in[8];
  const float* b2  = (const float*)d_in[9];
  float* out = (float*)d_out;

  char* wsb = (char*)d_ws;
  float* h    = (float*)(wsb);                        // 4,096,000 B
  float* lib  = (float*)(wsb + 4096000);              // 4,096,000 B
  float* yh   = (float*)(wsb + 8192000);              // 2,048,000 B
  float* wv   = (float*)(wsb + 10240000);             // 2,048,000 B
  int*   cols = (int*)(wsb + 12288000);               // 2,048,000 B
  int*   nnz  = (int*)(wsb + 14336000);               //    32,000 B
  unsigned short* w0s = (unsigned short*)(wsb + 14368000);  // 131,072 B
  unsigned* mask32 = (unsigned*)(wsb + 14499072 + 3520);    // align 16: 14502592
  // (14368000 + 131072 = 14499072; round up to 14502592 for 64B alignment)

  k_prep  <<<64,   256, 0, stream>>>(W0, w0s);
  k_front <<<2500, 256, 0, stream>>>(adj, x, w0s, b0, W1, b1, idx, yl,
                                     h, yh, out + 512000, mask32);
  k_ewp1  <<<2000, 256, 0, stream>>>(mask32, yh, h, cols, nnz, wv, lib);
  k_p2fin <<<2000, 256, 0, stream>>>(lib, h, cols, nnz, wv, W2, b2, out);
}

// Round 11
// 428.572 us; speedup vs baseline: 1.0381x; 1.0157x over previous
//
#include <hip/hip_runtime.h>
#include <math.h>

#define NROW   8000
#define NFEATD 512
#define NHID   128
#define NCLS   64
#define CAP    64
#define EPSV   1e-12f
#define ALV    0.1f
#define NTRAIN 500

typedef __attribute__((ext_vector_type(8))) short bf16x8;
typedef __attribute__((ext_vector_type(4))) float f32x4;
typedef __attribute__((address_space(1))) void as1_void;
typedef __attribute__((address_space(3))) void as3_void;

#define WAITVM8() asm volatile("s_waitcnt vmcnt(8)" ::: "memory")
#define WAITVM0() asm volatile("s_waitcnt vmcnt(0)" ::: "memory")

__device__ __forceinline__ float wsum(float v) {
#pragma unroll
  for (int off = 32; off > 0; off >>= 1) v += __shfl_xor(v, off, 64);
  return v;
}
__device__ __forceinline__ float wmax(float v) {
#pragma unroll
  for (int off = 32; off > 0; off >>= 1) v = fmaxf(v, __shfl_xor(v, off, 64));
  return v;
}
__device__ __forceinline__ unsigned short f2bf(float f) {   // RTN-even
  unsigned int u = __float_as_uint(f);
  unsigned int r = u + 0x7FFFu + ((u >> 16) & 1u);
  return (unsigned short)(r >> 16);
}

// ---------------------------------------------------------------------------
// Prep: cast W0 -> bf16 fragment-ordered w0s (128 KB, L2-hot). Grid 64 x 256.
// ---------------------------------------------------------------------------
__global__ __launch_bounds__(256) void k_prep(const float* __restrict__ W0,
                                              unsigned short* __restrict__ w0s) {
  int e = blockIdx.x * 1024 + threadIdx.x;
  for (int i = 0; i < 4; ++i, e += 256) {
    int c = e >> 12, n = (e >> 5) & 127, k = e & 31;
    w0s[e] = f2bf(W0[(size_t)(c * 32 + k) * NHID + n]);
  }
}

// ---------------------------------------------------------------------------
// Fused front-end. Grid 2500 x 256.
//   blockIdx % 5 == 4 : GEMM tile (500 x 16 rows): h = relu(x@W0+b0) via
//                       bf16 MFMA; then Pseudo/injection/softmax from LDS.
//   else              : scan role: each WAVE owns one adj row (32 KB) and
//                       streams it via global_load_lds DMA (bypasses the
//                       VGPR return path), double-buffered 8KB chunks with
//                       explicit vmcnt(8) staging. Zero atomics: ballot-
//                       prefix emission, count in a register, lane0 stores.
// ---------------------------------------------------------------------------
__global__ __launch_bounds__(256) void k_front(const float* __restrict__ adj,
                                               const float* __restrict__ x,
                                               const unsigned short* __restrict__ w0s,
                                               const float* __restrict__ b0,
                                               const float* __restrict__ W1,
                                               const float* __restrict__ b1,
                                               const int* __restrict__ idx,
                                               const float* __restrict__ yl,
                                               float* __restrict__ h,
                                               float* __restrict__ yh,
                                               float* __restrict__ outP,
                                               int* __restrict__ cols,
                                               int* __restrict__ gcnt) {
  __shared__ union {
    struct { float hs[16][NHID]; int ids[NTRAIN]; } g;  // GEMM role (10.2 KB)
    char stg[4][2][8000];                               // scan role (64 KB)
  } sm;
  const int t = threadIdx.x;
  const int lane = t & 63;
  const int w = t >> 6;
  const int g = blockIdx.x / 5;
  const int r = blockIdx.x - g * 5;

  if (r == 4) {
    // ---------------- GEMM + pseudo/softmax role ----------------
    const int m = lane & 15, q = lane >> 4;
    const int row0 = g * 16;
    const int wcol = w * 32;
    for (int i = t; i < NTRAIN; i += 256) sm.g.ids[i] = idx[i];
    const float* ap = x + (size_t)(row0 + m) * NFEATD + q * 8;
    f32x4 acc0 = {0.f, 0.f, 0.f, 0.f}, acc1 = {0.f, 0.f, 0.f, 0.f};

    for (int c = 0; c < 16; ++c) {
      float4 a0 = *(const float4*)(ap + c * 32);
      float4 a1 = *(const float4*)(ap + c * 32 + 4);
      bf16x8 bv0 = *(const bf16x8*)(w0s + c * 4096 + (wcol + m) * 32 + q * 8);
      bf16x8 bv1 = *(const bf16x8*)(w0s + c * 4096 + (wcol + 16 + m) * 32 + q * 8);
      bf16x8 av;
      av[0] = (short)f2bf(a0.x); av[1] = (short)f2bf(a0.y);
      av[2] = (short)f2bf(a0.z); av[3] = (short)f2bf(a0.w);
      av[4] = (short)f2bf(a1.x); av[5] = (short)f2bf(a1.y);
      av[6] = (short)f2bf(a1.z); av[7] = (short)f2bf(a1.w);
      acc0 = __builtin_amdgcn_mfma_f32_16x16x32_bf16(av, bv0, acc0, 0, 0, 0);
      acc1 = __builtin_amdgcn_mfma_f32_16x16x32_bf16(av, bv1, acc1, 0, 0, 0);
    }
    const float bc0 = b0[wcol + m], bc1 = b0[wcol + 16 + m];
#pragma unroll
    for (int reg = 0; reg < 4; ++reg) {
      int lr = q * 4 + reg;
      float h0v = fmaxf(acc0[reg] + bc0, 0.f);
      float h1v = fmaxf(acc1[reg] + bc1, 0.f);
      h[(size_t)(row0 + lr) * NHID + wcol + m] = h0v;
      h[(size_t)(row0 + lr) * NHID + wcol + 16 + m] = h1v;
      sm.g.hs[lr][wcol + m] = h0v;
      sm.g.hs[lr][wcol + 16 + m] = h1v;
    }
    __syncthreads();
    const float b1v = b1[lane];
#pragma unroll
    for (int rr = 0; rr < 4; ++rr) {
      const int lr = w * 4 + rr;
      const int grow = row0 + lr;
      float acc = b1v;
#pragma unroll 8
      for (int k = 0; k < NHID; ++k) acc += sm.g.hs[lr][k] * W1[k * NCLS + lane];
      int lo = 0, hi = NTRAIN;
      while (lo < hi) { int mid = (lo + hi) >> 1; if (sm.g.ids[mid] < grow) lo = mid + 1; else hi = mid; }
      int lb = lo; hi = NTRAIN;
      while (lo < hi) { int mid = (lo + hi) >> 1; if (sm.g.ids[mid] <= grow) lo = mid + 1; else hi = mid; }
      int count = lo - lb;
      if (count) acc += ALV * (float)count * yl[(size_t)grow * NCLS + lane];
      outP[(size_t)grow * NCLS + lane] = acc;
      float mx = wmax(acc);
      float e = __expf(acc - mx);
      float s = wsum(e);
      yh[(size_t)grow * NCLS + lane] = e / s;
    }
  } else {
    // ---------------- Scan role: DMA-staged, wave-owns-row ----------------
    const int srow = (g * 4 + r) * 4 + w;          // 2000 blocks x 4 waves = 8000 rows
    const char* gbase = (const char*)(adj + (size_t)srow * NROW);
    char* bufA = sm.stg[w][0];
    char* bufB = sm.stg[w][1];
    int* rowcols = cols + srow * CAP;
    int tot = 0;
    const unsigned long long below = (1ULL << lane) - 1ULL;

    // issue chunk c (500 f32x4 = 8000 B) into buf: 7 full insts + 1 x 52-lane
#define ISSUE(c, buf)                                                          \
    {                                                                          \
      const char* gb = gbase + (c) * 8000;                                     \
      _Pragma("unroll")                                                        \
      for (int k = 0; k < 7; ++k)                                              \
        __builtin_amdgcn_global_load_lds((as1_void*)(gb + k * 1024 + lane * 16),\
                                         (as3_void*)((buf) + k * 1024), 16, 0, 0);\
      if (lane < 52)                                                           \
        __builtin_amdgcn_global_load_lds((as1_void*)(gb + 7168 + lane * 16),   \
                                         (as3_void*)((buf) + 7168), 16, 0, 0); \
    }

#define CONSUME(c, buf)                                                        \
    {                                                                          \
      _Pragma("unroll")                                                        \
      for (int it = 0; it < 8; ++it) {                                         \
        f32x4 v = {0.f, 0.f, 0.f, 0.f};                                        \
        if (it < 7 || lane < 52)                                               \
          v = *(const f32x4*)((buf) + it * 1024 + lane * 16);                  \
        bool nz = (v[0] != 0.f) | (v[1] != 0.f) | (v[2] != 0.f) | (v[3] != 0.f);\
        unsigned long long any = __ballot(nz);                                 \
        if (any) {                                                             \
          unsigned long long m0 = __ballot(v[0] != 0.f);                       \
          unsigned long long m1 = __ballot(v[1] != 0.f);                       \
          unsigned long long m2 = __ballot(v[2] != 0.f);                       \
          unsigned long long m3 = __ballot(v[3] != 0.f);                       \
          int b0c = tot;                                                       \
          int b1c = b0c + __popcll(m0);                                        \
          int b2c = b1c + __popcll(m1);                                        \
          int b3c = b2c + __popcll(m2);                                        \
          tot = b3c + __popcll(m3);                                            \
          int p4 = ((c) * 500 + it * 64 + lane) << 2;                          \
          if (v[0] != 0.f) { int p = b0c + __popcll(m0 & below); if (p < CAP) rowcols[p] = p4; }     \
          if (v[1] != 0.f) { int p = b1c + __popcll(m1 & below); if (p < CAP) rowcols[p] = p4 + 1; } \
          if (v[2] != 0.f) { int p = b2c + __popcll(m2 & below); if (p < CAP) rowcols[p] = p4 + 2; } \
          if (v[3] != 0.f) { int p = b3c + __popcll(m3 & below); if (p < CAP) rowcols[p] = p4 + 3; } \
        }                                                                      \
      }                                                                        \
    }

    ISSUE(0, bufA);
    ISSUE(1, bufB);
    WAITVM8(); CONSUME(0, bufA);
    ISSUE(2, bufA);
    WAITVM8(); CONSUME(1, bufB);
    ISSUE(3, bufB);
    WAITVM8(); CONSUME(2, bufA);
    WAITVM0(); CONSUME(3, bufB);

    if (lane == 0) gcnt[srow] = tot < CAP ? tot : CAP;
#undef ISSUE
#undef CONSUME
  }
}

// ---------------------------------------------------------------------------
// Fused edge weights + propagation layer 1. Grid 2000 x 256, wave per row.
// ---------------------------------------------------------------------------
__global__ __launch_bounds__(256) void k_ewp1(const float* __restrict__ yh,
                                              const float* __restrict__ h,
                                              const int* __restrict__ cols,
                                              const int* __restrict__ gcnt,
                                              float* __restrict__ wv,
                                              float* __restrict__ lib) {
  __shared__ float yrow[4][NCLS];
  const int w = threadIdx.x >> 6, lane = threadIdx.x & 63;
  const int row = blockIdx.x * 4 + w;
  const int ne = min(gcnt[row], CAP);
  int jv = 0;
  if (lane < ne) jv = cols[row * CAP + lane];
  yrow[w][lane] = yh[(size_t)row * NCLS + lane];
  __syncthreads();
  float dot = 0.f;
  if (lane < ne) {
    const float4* jp = (const float4*)(yh + (size_t)jv * NCLS);
    const float4* rp = (const float4*)yrow[w];
#pragma unroll
    for (int c4 = 0; c4 < NCLS / 4; ++c4) {
      float4 a = rp[c4], b = jp[c4];
      dot += a.x * b.x + a.y * b.y + a.z * b.z + a.w * b.w;
    }
  }
  float rs = wsum(dot);
  float myw = dot * (1.f / fmaxf(rs, EPSV));
  if (lane < ne) wv[row * CAP + lane] = myw;
  float a0 = 0.f, a1 = 0.f;
  for (int e = 0; e < ne; ++e) {
    int j = __shfl(jv, e, 64);
    float wt = __shfl(myw, e, 64);
    a0 += wt * h[(size_t)j * NHID + lane];
    a1 += wt * h[(size_t)j * NHID + 64 + lane];
  }
  float v0 = (1.f - ALV) * a0 + ALV * h[(size_t)row * NHID + lane];
  float v1 = (1.f - ALV) * a1 + ALV * h[(size_t)row * NHID + 64 + lane];
  float s = wsum(v0 * v0 + v1 * v1);
  float inv = 1.f / fmaxf(sqrtf(s), EPSV);
  lib[(size_t)row * NHID + lane] = v0 * inv;
  lib[(size_t)row * NHID + 64 + lane] = v1 * inv;
}

// ---------------------------------------------------------------------------
// Fused propagation layer 2 + final head. Grid 2000 x 256, wave per row.
// ---------------------------------------------------------------------------
__global__ __launch_bounds__(256) void k_p2fin(const float* __restrict__ lib,
                                               const float* __restrict__ h,
                                               const int* __restrict__ cols,
                                               const int* __restrict__ gcnt,
                                               const float* __restrict__ wv,
                                               const float* __restrict__ W2,
                                               const float* __restrict__ b2,
                                               float* __restrict__ out) {
  __shared__ float lrow[4][NHID];
  const int w = threadIdx.x >> 6, lane = threadIdx.x & 63;
  const int row = blockIdx.x * 4 + w;
  const int ne = min(gcnt[row], CAP);
  int jv = 0; float wt = 0.f;
  if (lane < ne) { jv = cols[row * CAP + lane]; wt = wv[row * CAP + lane]; }
  float a0 = 0.f, a1 = 0.f;
  for (int e = 0; e < ne; ++e) {
    int j = __shfl(jv, e, 64);
    float we = __shfl(wt, e, 64);
    a0 += we * lib[(size_t)j * NHID + lane];
    a1 += we * lib[(size_t)j * NHID + 64 + lane];
  }
  float v0 = (1.f - ALV) * a0 + ALV * h[(size_t)row * NHID + lane];
  float v1 = (1.f - ALV) * a1 + ALV * h[(size_t)row * NHID + 64 + lane];
  float s = wsum(v0 * v0 + v1 * v1);
  float inv = 1.f / fmaxf(sqrtf(s), EPSV);
  lrow[w][lane] = v0 * inv;
  lrow[w][lane + 64] = v1 * inv;
  __syncthreads();
  float acc = b2[lane];
#pragma unroll 8
  for (int k = 0; k < NHID; ++k) acc += lrow[w][k] * W2[k * NCLS + lane];
  float mx = wmax(acc);
  float l = acc - mx;
  float se = wsum(__expf(l));
  out[(size_t)row * NCLS + lane] = l - __logf(se);
}

// ---------------------------------------------------------------------------
extern "C" void kernel_launch(void* const* d_in, const int* in_sizes, int n_in,
                              void* d_out, int out_size, void* d_ws, size_t ws_size,
                              hipStream_t stream) {
  const float* x   = (const float*)d_in[0];
  const float* adj = (const float*)d_in[1];
  const float* yl  = (const float*)d_in[2];
  const int*   idx = (const int*)d_in[3];
  const float* W0  = (const float*)d_in[4];
  const float* b0  = (const float*)d_in[5];
  const float* W1  = (const float*)d_in[6];
  const float* b1  = (const float*)d_in[7];
  const float* W2  = (const float*)d_in[8];
  const float* b2  = (const float*)d_in[9];
  float* out = (float*)d_out;

  char* wsb = (char*)d_ws;
  float* h    = (float*)(wsb);                  // 4,096,000 B
  float* lib  = (float*)(wsb + 4096000);        // 4,096,000 B
  float* yh   = (float*)(wsb + 8192000);        // 2,048,000 B
  float* wv   = (float*)(wsb + 10240000);       // 2,048,000 B
  int*   cols = (int*)(wsb + 12288000);         // 2,048,000 B
  int*   gcnt = (int*)(wsb + 14336000);         //    32,000 B
  unsigned short* w0s = (unsigned short*)(wsb + 14368000);  // 131,072 B

  k_prep  <<<64,   256, 0, stream>>>(W0, w0s);
  k_front <<<2500, 256, 0, stream>>>(adj, x, w0s, b0, W1, b1, idx, yl,
                                     h, yh, out + 512000, cols, gcnt);
  k_ewp1  <<<2000, 256, 0, stream>>>(yh, h, cols, gcnt, wv, lib);
  k_p2fin <<<2000, 256, 0, stream>>>(lib, h, cols, gcnt, wv, W2, b2, out);
}

// Round 12
// 421.106 us; speedup vs baseline: 1.0565x; 1.0177x over previous
//
#include <hip/hip_runtime.h>
#include <math.h>

#define NROW   8000
#define NFEATD 512
#define NHID   128
#define NCLS   64
#define CAP    64
#define EPSV   1e-12f
#define ALV    0.1f
#define NTRAIN 500

typedef __attribute__((ext_vector_type(8))) short bf16x8;
typedef __attribute__((ext_vector_type(4))) float f32x4;

__device__ __forceinline__ float wsum(float v) {
#pragma unroll
  for (int off = 32; off > 0; off >>= 1) v += __shfl_xor(v, off, 64);
  return v;
}
__device__ __forceinline__ float wmax(float v) {
#pragma unroll
  for (int off = 32; off > 0; off >>= 1) v = fmaxf(v, __shfl_xor(v, off, 64));
  return v;
}
__device__ __forceinline__ unsigned short f2bf(float f) {   // RTN-even
  unsigned int u = __float_as_uint(f);
  unsigned int r = u + 0x7FFFu + ((u >> 16) & 1u);
  return (unsigned short)(r >> 16);
}

// ---------------------------------------------------------------------------
// Prep: cast W0 -> bf16 fragment-ordered w0s (128 KB, L2-hot) AND zero the
// per-row edge counters (ws is poisoned 0xAA every iteration). Grid 64 x 256.
// ---------------------------------------------------------------------------
__global__ __launch_bounds__(256) void k_prep(const float* __restrict__ W0,
                                              unsigned short* __restrict__ w0s,
                                              int* __restrict__ gcnt) {
  int e = blockIdx.x * 1024 + threadIdx.x;
  for (int i = 0; i < 4; ++i, e += 256) {
    int c = e >> 12, n = (e >> 5) & 127, k = e & 31;
    w0s[e] = f2bf(W0[(size_t)(c * 32 + k) * NHID + n]);
  }
  int z = blockIdx.x * 256 + threadIdx.x;
  if (z < NROW) gcnt[z] = 0;
}

// ---------------------------------------------------------------------------
// Fused front-end, block-role partitioned. Grid 8500 x 256.  [best: R7]
//   blockIdx % 17 == 16 : GEMM tile (500 x 16 rows): h = relu(x@W0+b0) via
//                         bf16 MFMA; then Pseudo = h@W1+b1 (+injection) and
//                         y_hat = softmax(Pseudo) for the same rows from LDS.
//   else                 : adj row scan -> cols/gcnt. Barrier-free: 8
//                         coalesced float4 loads in flight; each (rare)
//                         nonzero claims a slot via global atomicAdd.
// Scan rate ~1.7 TB/s apparent = the demonstrated environmental ceiling for
// this read pattern (8 structures / 3 load mechanisms all converge here).
// ---------------------------------------------------------------------------
__global__ __launch_bounds__(256) void k_front(const float* __restrict__ adj,
                                               const float* __restrict__ x,
                                               const unsigned short* __restrict__ w0s,
                                               const float* __restrict__ b0,
                                               const float* __restrict__ W1,
                                               const float* __restrict__ b1,
                                               const int* __restrict__ idx,
                                               const float* __restrict__ yl,
                                               float* __restrict__ h,
                                               float* __restrict__ yh,
                                               float* __restrict__ outP,
                                               int* __restrict__ cols,
                                               int* __restrict__ gcnt) {
  __shared__ float hs[16][NHID];   // GEMM role only (8 KB)
  __shared__ int ids[NTRAIN];      // GEMM role only (2 KB)
  const int t = threadIdx.x;
  const int lane = t & 63;
  const int g = blockIdx.x / 17;
  const int r = blockIdx.x - g * 17;

  if (r == 16) {
    // ---------------- GEMM + pseudo/softmax role ----------------
    const int w = t >> 6;
    const int m = lane & 15, q = lane >> 4;
    const int row0 = g * 16;
    const int wcol = w * 32;
    for (int i = t; i < NTRAIN; i += 256) ids[i] = idx[i];
    const float* ap = x + (size_t)(row0 + m) * NFEATD + q * 8;
    f32x4 acc0 = {0.f, 0.f, 0.f, 0.f}, acc1 = {0.f, 0.f, 0.f, 0.f};

    for (int c = 0; c < 16; ++c) {
      float4 a0 = *(const float4*)(ap + c * 32);
      float4 a1 = *(const float4*)(ap + c * 32 + 4);
      bf16x8 bv0 = *(const bf16x8*)(w0s + c * 4096 + (wcol + m) * 32 + q * 8);
      bf16x8 bv1 = *(const bf16x8*)(w0s + c * 4096 + (wcol + 16 + m) * 32 + q * 8);
      bf16x8 av;
      av[0] = (short)f2bf(a0.x); av[1] = (short)f2bf(a0.y);
      av[2] = (short)f2bf(a0.z); av[3] = (short)f2bf(a0.w);
      av[4] = (short)f2bf(a1.x); av[5] = (short)f2bf(a1.y);
      av[6] = (short)f2bf(a1.z); av[7] = (short)f2bf(a1.w);
      acc0 = __builtin_amdgcn_mfma_f32_16x16x32_bf16(av, bv0, acc0, 0, 0, 0);
      acc1 = __builtin_amdgcn_mfma_f32_16x16x32_bf16(av, bv1, acc1, 0, 0, 0);
    }
    const float bc0 = b0[wcol + m], bc1 = b0[wcol + 16 + m];
#pragma unroll
    for (int reg = 0; reg < 4; ++reg) {
      int lr = q * 4 + reg;
      float h0v = fmaxf(acc0[reg] + bc0, 0.f);
      float h1v = fmaxf(acc1[reg] + bc1, 0.f);
      h[(size_t)(row0 + lr) * NHID + wcol + m] = h0v;
      h[(size_t)(row0 + lr) * NHID + wcol + 16 + m] = h1v;
      hs[lr][wcol + m] = h0v;
      hs[lr][wcol + 16 + m] = h1v;
    }
    __syncthreads();
    const float b1v = b1[lane];
#pragma unroll
    for (int rr = 0; rr < 4; ++rr) {
      const int lr = w * 4 + rr;
      const int grow = row0 + lr;
      float acc = b1v;
#pragma unroll 8
      for (int k = 0; k < NHID; ++k) acc += hs[lr][k] * W1[k * NCLS + lane];
      int lo = 0, hi = NTRAIN;
      while (lo < hi) { int mid = (lo + hi) >> 1; if (ids[mid] < grow) lo = mid + 1; else hi = mid; }
      int lb = lo; hi = NTRAIN;
      while (lo < hi) { int mid = (lo + hi) >> 1; if (ids[mid] <= grow) lo = mid + 1; else hi = mid; }
      int count = lo - lb;
      if (count) acc += ALV * (float)count * yl[(size_t)grow * NCLS + lane];
      outP[(size_t)grow * NCLS + lane] = acc;
      float mx = wmax(acc);
      float e = __expf(acc - mx);
      float s = wsum(e);
      yh[(size_t)grow * NCLS + lane] = e / s;
    }
  } else {
    // ---------------- CSR role (barrier-free, atomic slot claim) ----------
    const int row = g * 16 + r;
    const f32x4* rp = (const f32x4*)(adj + (size_t)row * NROW);
    int* rowcols = cols + row * CAP;
    const f32x4 z4 = {0.f, 0.f, 0.f, 0.f};
    f32x4 v[8];
#pragma unroll
    for (int i = 0; i < 7; ++i) v[i] = __builtin_nontemporal_load(rp + t + (i << 8));
    v[7] = (t < 208) ? __builtin_nontemporal_load(rp + t + 1792) : z4;  // 2000 f32x4/row
#pragma unroll
    for (int i = 0; i < 8; ++i) {
      f32x4 w = v[i];
      if (w[0] != 0.f || w[1] != 0.f || w[2] != 0.f || w[3] != 0.f) {
        int bcol = (t + (i << 8)) << 2;
#pragma unroll
        for (int j = 0; j < 4; ++j) {
          if (w[j] != 0.f) {
            int p = atomicAdd(gcnt + row, 1);
            if (p < CAP) rowcols[p] = bcol + j;
          }
        }
      }
    }
  }
}

// ---------------------------------------------------------------------------
// Fused edge weights + propagation layer 1. Grid 2000 x 256, wave per row.
// Dot phase: lane e owns edge e's full 64-class dot (parallel, one wsum).
// ---------------------------------------------------------------------------
__global__ __launch_bounds__(256) void k_ewp1(const float* __restrict__ yh,
                                              const float* __restrict__ h,
                                              const int* __restrict__ cols,
                                              const int* __restrict__ gcnt,
                                              float* __restrict__ wv,
                                              float* __restrict__ lib) {
  __shared__ float yrow[4][NCLS];
  const int w = threadIdx.x >> 6, lane = threadIdx.x & 63;
  const int row = blockIdx.x * 4 + w;
  const int ne = min(gcnt[row], CAP);
  int jv = 0;
  if (lane < ne) jv = cols[row * CAP + lane];
  yrow[w][lane] = yh[(size_t)row * NCLS + lane];
  __syncthreads();
  float dot = 0.f;
  if (lane < ne) {
    const float4* jp = (const float4*)(yh + (size_t)jv * NCLS);
    const float4* rp = (const float4*)yrow[w];
#pragma unroll
    for (int c4 = 0; c4 < NCLS / 4; ++c4) {
      float4 a = rp[c4], b = jp[c4];
      dot += a.x * b.x + a.y * b.y + a.z * b.z + a.w * b.w;
    }
  }
  float rs = wsum(dot);
  float myw = dot * (1.f / fmaxf(rs, EPSV));
  if (lane < ne) wv[row * CAP + lane] = myw;
  float a0 = 0.f, a1 = 0.f;
  for (int e = 0; e < ne; ++e) {
    int j = __shfl(jv, e, 64);
    float wt = __shfl(myw, e, 64);
    a0 += wt * h[(size_t)j * NHID + lane];
    a1 += wt * h[(size_t)j * NHID + 64 + lane];
  }
  float v0 = (1.f - ALV) * a0 + ALV * h[(size_t)row * NHID + lane];
  float v1 = (1.f - ALV) * a1 + ALV * h[(size_t)row * NHID + 64 + lane];
  float s = wsum(v0 * v0 + v1 * v1);
  float inv = 1.f / fmaxf(sqrtf(s), EPSV);
  lib[(size_t)row * NHID + lane] = v0 * inv;
  lib[(size_t)row * NHID + 64 + lane] = v1 * inv;
}

// ---------------------------------------------------------------------------
// Fused propagation layer 2 + final head. Grid 2000 x 256, wave per row.
// ---------------------------------------------------------------------------
__global__ __launch_bounds__(256) void k_p2fin(const float* __restrict__ lib,
                                               const float* __restrict__ h,
                                               const int* __restrict__ cols,
                                               const int* __restrict__ gcnt,
                                               const float* __restrict__ wv,
                                               const float* __restrict__ W2,
                                               const float* __restrict__ b2,
                                               float* __restrict__ out) {
  __shared__ float lrow[4][NHID];
  const int w = threadIdx.x >> 6, lane = threadIdx.x & 63;
  const int row = blockIdx.x * 4 + w;
  const int ne = min(gcnt[row], CAP);
  int jv = 0; float wt = 0.f;
  if (lane < ne) { jv = cols[row * CAP + lane]; wt = wv[row * CAP + lane]; }
  float a0 = 0.f, a1 = 0.f;
  for (int e = 0; e < ne; ++e) {
    int j = __shfl(jv, e, 64);
    float we = __shfl(wt, e, 64);
    a0 += we * lib[(size_t)j * NHID + lane];
    a1 += we * lib[(size_t)j * NHID + 64 + lane];
  }
  float v0 = (1.f - ALV) * a0 + ALV * h[(size_t)row * NHID + lane];
  float v1 = (1.f - ALV) * a1 + ALV * h[(size_t)row * NHID + 64 + lane];
  float s = wsum(v0 * v0 + v1 * v1);
  float inv = 1.f / fmaxf(sqrtf(s), EPSV);
  lrow[w][lane] = v0 * inv;
  lrow[w][lane + 64] = v1 * inv;
  __syncthreads();
  float acc = b2[lane];
#pragma unroll 8
  for (int k = 0; k < NHID; ++k) acc += lrow[w][k] * W2[k * NCLS + lane];
  float mx = wmax(acc);
  float l = acc - mx;
  float se = wsum(__expf(l));
  out[(size_t)row * NCLS + lane] = l - __logf(se);
}

// ---------------------------------------------------------------------------
extern "C" void kernel_launch(void* const* d_in, const int* in_sizes, int n_in,
                              void* d_out, int out_size, void* d_ws, size_t ws_size,
                              hipStream_t stream) {
  const float* x   = (const float*)d_in[0];
  const float* adj = (const float*)d_in[1];
  const float* yl  = (const float*)d_in[2];
  const int*   idx = (const int*)d_in[3];
  const float* W0  = (const float*)d_in[4];
  const float* b0  = (const float*)d_in[5];
  const float* W1  = (const float*)d_in[6];
  const float* b1  = (const float*)d_in[7];
  const float* W2  = (const float*)d_in[8];
  const float* b2  = (const float*)d_in[9];
  float* out = (float*)d_out;

  char* wsb = (char*)d_ws;
  float* h    = (float*)(wsb);                  // 4,096,000 B
  float* lib  = (float*)(wsb + 4096000);        // 4,096,000 B
  float* yh   = (float*)(wsb + 8192000);        // 2,048,000 B
  float* wv   = (float*)(wsb + 10240000);       // 2,048,000 B
  int*   cols = (int*)(wsb + 12288000);         // 2,048,000 B
  int*   gcnt = (int*)(wsb + 14336000);         //    32,000 B
  unsigned short* w0s = (unsigned short*)(wsb + 14368000);  // 131,072 B

  k_prep  <<<64,   256, 0, stream>>>(W0, w0s, gcnt);
  k_front <<<8500, 256, 0, stream>>>(adj, x, w0s, b0, W1, b1, idx, yl,
                                     h, yh, out + 512000, cols, gcnt);
  k_ewp1  <<<2000, 256, 0, stream>>>(yh, h, cols, gcnt, wv, lib);
  k_p2fin <<<2000, 256, 0, stream>>>(lib, h, cols, gcnt, wv, W2, b2, out);
}